// Round 5
// baseline (4993.129 us; speedup 1.0000x reference)
//
#include <hip/hip_runtime.h>

// ---------------------------------------------------------------------------
// NeuralCA, persistent kernel: all 40 steps in ONE launch.
//   Block = 2 image rows (448 blocks, 2/CU). Weights live in registers for
//   the whole run. Steps are ordered per-block by neighbor-only flag sync
//   (done[blk] = published state version, agent-scope release/acquire) --
//   no global barrier, the step wavefront pipelines across blocks.
//   waves 0-1 (G1):  h1 = relu(W_eff * im2col(x) + b1)   W_eff regs
//   waves 2-3 (G23): G2 on h1[j-1]; G3+epilogue on h2[j-2]
//   x = clamp(x + dx, 0, 1); fp32 master (NHWC) + bf16 shadow, ping-pong.
// ---------------------------------------------------------------------------

typedef __attribute__((ext_vector_type(8))) short short8;
typedef __attribute__((ext_vector_type(4))) float float4v;
typedef __attribute__((ext_vector_type(4))) unsigned uint4v;

#define MFMA16(a, b, c) __builtin_amdgcn_mfma_f32_16x16x32_bf16((a), (b), (c), 0, 0, 0)

__device__ __forceinline__ short f2bf(float f) {
  unsigned u = __builtin_bit_cast(unsigned, f);
  return (short)((u + 0x8000u) >> 16);     // round-half-up
}

// packed f32x2 -> bf16x2 (gfx950 v_cvt_pk_bf16_f32; fallback: manual)
__device__ __forceinline__ unsigned pk2bf(float a, float b) {
#if __has_builtin(__builtin_amdgcn_cvt_pk_bf16_f32)
  typedef __attribute__((ext_vector_type(2))) __bf16 bf2;
  bf2 r = __builtin_amdgcn_cvt_pk_bf16_f32(a, b);
  return __builtin_bit_cast(unsigned, r);
#else
  unsigned ua = __builtin_bit_cast(unsigned, a), ub = __builtin_bit_cast(unsigned, b);
  return ((ua + 0x8000u) >> 16) | (((ub + 0x8000u) >> 16) << 16);
#endif
}

__device__ __forceinline__ void async16(const void* g, void* l) {
  __builtin_amdgcn_global_load_lds((const __attribute__((address_space(1))) void*)g,
                                   (__attribute__((address_space(3))) void*)l,
                                   16, 0, 0);
}

// LDS-only barrier: no vmcnt drain
__device__ __forceinline__ void sync_lds() {
  asm volatile("s_waitcnt lgkmcnt(0)\n\ts_barrier" ::: "memory");
}

// ---- workspace layout (bytes) ----
#define WS_WE    0          // W_eff^T [128][168] bf16 (K pad 144->168, zeros)
#define WS_W2    43008      // W2^T    [128][136] bf16 (K sigma-permuted)
#define WS_W3    77824      // W3^T    [ 16][136] bf16 (sigma-perm, pad 2560)
#define WS_B1    82944      // b1 sigma-permuted f32 [128]
#define WS_B2    83456      // b2 sigma-permuted f32 [128]
#define WS_X32A  83968
#define WS_X32B  12929024
#define WS_X16A  25774080
#define WS_X16B  32196608
#define WS_DONE  38619136   // unsigned done[512]

// ---------------------------------------------------------------------------
__global__ void prep_x(const float* __restrict__ x, float* __restrict__ x32,
                       short* __restrict__ x16, unsigned* __restrict__ done) {
  if (blockIdx.x < 2) done[blockIdx.x * 256 + threadIdx.x] = 0;  // sync flags
  int i = blockIdx.x * 256 + threadIdx.x;          // exactly 3211264 threads
  int w = i % 224;
  int h = (i / 224) % 224;
  int c = (i / 50176) & 15;
  int bb = i / 802816;
  float v = x[i];
  int o = ((bb * 224 + h) * 224 + w) * 16 + c;     // NHWC
  x32[o] = v;
  x16[o] = f2bf(v);
}

// sigma: stored position p holds channel chan(p) = 16*(p&7) + (p>>3)
__global__ void prep_w(const float* __restrict__ wp, const float* __restrict__ w1,
                       const float* __restrict__ b1, const float* __restrict__ w2,
                       const float* __restrict__ b2, const float* __restrict__ w3,
                       short* __restrict__ wE, short* __restrict__ w2t,
                       short* __restrict__ w3t, float* __restrict__ b1p,
                       float* __restrict__ b2p) {
  int i = blockIdx.x * 256 + threadIdx.x;          // exactly 41728 threads
  if (i < 21504) {                                  // W_eff^T [o=128][k=168]
    int o = i / 168, k = i % 168;
    float v = 0.f;
    if (k < 144) {
      int off = k >> 4, c = k & 15;                 // k = offset*16 + c
      for (int c3 = 0; c3 < 48; ++c3)
        v += w1[o * 48 + c3] * wp[c3 * 144 + c * 9 + off];
    }
    wE[i] = f2bf(v);
  } else if (i < 38912) {                           // W2^T perm [n=128][kk=136]
    int j = i - 21504;
    int n = j / 136, kk = j % 136;
    float v = 0.f;
    if (kk < 128) { int ch = 16 * (kk & 7) + (kk >> 3); v = w2[n * 128 + ch]; }
    w2t[j] = f2bf(v);
  } else if (i < 41472) {                           // W3^T perm, padded to 2560
    int j = i - 38912;
    float v = 0.f;
    if (j < 2176) {
      int n = j / 136, kk = j % 136;
      if (kk < 128) { int ch = 16 * (kk & 7) + (kk >> 3); v = w3[n * 128 + ch]; }
    }
    w3t[j] = f2bf(v);
  } else if (i < 41600) {
    int p = i - 41472;
    b1p[p] = b1[16 * (p & 7) + (p >> 3)];
  } else {
    int p = i - 41600;
    b2p[p] = b2[16 * (p & 7) + (p >> 3)];
  }
}

// ---------------------------------------------------------------------------
__global__ __launch_bounds__(256, 2) void ca_persist(
    const short* __restrict__ wEg, const short* __restrict__ w2g,
    const short* __restrict__ w3g, const float* __restrict__ b1p,
    const float* __restrict__ b2p, float* __restrict__ X32a,
    short* __restrict__ X16a, float* __restrict__ X32b,
    short* __restrict__ X16b, float* __restrict__ dout,
    unsigned* __restrict__ done) {
  __shared__ short sXH[4 * 3616];       // 28928 B  halo: 4 rows x 226 x 16ch
  __shared__ short sBUF[2 * 2 * 2176];  // 17408 B  h1 mailbox dbuf
  __shared__ short sH2[2 * 2 * 2176];   // 17408 B  h2 dbuf
  // total 63744 B -> 2 blocks/CU; 448 blocks <= 512 capacity (co-resident)

  const int tid = threadIdx.x;
  const int lane = tid & 63;
  const int wv = tid >> 6;
  const int c16 = lane & 15;
  const int q = lane >> 4;
  const int q8 = q * 8;
  const int qh = q >> 1;
  const int c0 = (q & 1) * 8;

  const int blk = blockIdx.x;           // 448 = 4 batches x 112 rowgroups
  const int b = blk / 112;
  const int rg = blk % 112;
  const int h0 = rg * 2;
  const bool hasUp = rg > 0, hasDn = rg < 111;

  const short8 z8 = {0, 0, 0, 0, 0, 0, 0, 0};
  if (tid < 16) {   // zero edge cols (image col -1 and 224); staging never
    int hr = tid >> 2, wch = tid & 3;   // touches them, so once is enough
    int colb = (wch < 2) ? 0 : 225;
    *(short8*)((char*)sXH + hr * 7232 + colb * 32 + (wch & 1) * 16) = z8;
  }

  // ---- weights -> registers, once for all 40 steps ----
  short8 wf[5][8];                      // G1 role (waves 0-1)
  short8 w2f[4][8];                     // G23 role (waves 2-3)
  short8 w3f[4];
  float4v bA, bB;
  if (wv < 2) {
#pragma unroll
    for (int kc = 0; kc < 5; ++kc)
#pragma unroll
      for (int nt = 0; nt < 8; ++nt)
        wf[kc][nt] = *(const short8*)(wEg + (nt * 16 + c16) * 168 + kc * 32 + q8);
    bA = *(const float4v*)(b1p + c16 * 8);
    bB = *(const float4v*)(b1p + c16 * 8 + 4);
  } else {
#pragma unroll
    for (int kc = 0; kc < 4; ++kc)
#pragma unroll
      for (int nt = 0; nt < 8; ++nt)
        w2f[kc][nt] = *(const short8*)(w2g + (nt * 16 + c16) * 136 + kc * 32 + q8);
#pragma unroll
    for (int kc = 0; kc < 4; ++kc)
      w3f[kc] = *(const short8*)(w3g + c16 * 136 + kc * 32 + q8);
    bA = *(const float4v*)(b2p + c16 * 8);
    bB = *(const float4v*)(b2p + c16 * 8 + 4);
  }

  for (int s = 0; s < 40; ++s) {
    const int sb = s & 1;
    const float* xs32 = sb ? X32b : X32a;
    const short* xs16 = sb ? X16b : X16a;
    float* xd32 = sb ? X32a : X32b;
    short* xd16 = sb ? X16a : X16b;
    const bool last = (s == 39);

    // ---- wait for neighbors to publish state version s ----
    if (tid == 0 && s > 0) {
      if (hasUp)
        while (__hip_atomic_load(&done[blk - 1], __ATOMIC_RELAXED,
                                 __HIP_MEMORY_SCOPE_AGENT) < (unsigned)s)
          asm volatile("s_sleep 2");
      if (hasDn)
        while (__hip_atomic_load(&done[blk + 1], __ATOMIC_RELAXED,
                                 __HIP_MEMORY_SCOPE_AGENT) < (unsigned)s)
          asm volatile("s_sleep 2");
      __builtin_amdgcn_fence(__ATOMIC_ACQUIRE, "agent");
    }
    __syncthreads();

    // ---- stage halo: 4 rows x 7 chunks (1KB); OOB rows -> zeros ----
    for (int t = wv; t < 28; t += 4) {
      int hr = t / 7, ck = t % 7;
      int hh = h0 - 1 + hr;
      char* l = (char*)sXH + hr * 7232 + 32 + ck * 1024;
      if (hh >= 0 && hh < 224) {
        const char* g = (const char*)xs16 + ((size_t)(b * 224 + hh) * 224) * 32 + ck * 1024;
        async16(g + lane * 16, l);
      } else {
        *(short8*)(l + lane * 16) = z8;
      }
    }
    __syncthreads();                    // drains vmcnt: halo ready

    if (wv < 2) {
      // =============== G1 waves: conv3x3+MLP1 fused ====================
      for (int j = 0; j < 16; ++j) {
        if (j < 14) {
          const int t = 2 * j + wv;
          const int rr = t / 14, cb = (t % 14) * 16;
          const int hbase = (rr * 226 + cb) * 16;
          float4v acc[8];
#pragma unroll
          for (int nt = 0; nt < 8; ++nt) acc[nt] = (float4v){0.f, 0.f, 0.f, 0.f};
#pragma unroll
          for (int kc = 0; kc < 5; ++kc) {
            int off = kc * 2 + qh;
            if (off > 8) off = 8;       // K 144..159 hit zero rows of W_eff
            int dy = (off * 11) >> 5;   // off/3
            int dxx = off - dy * 3;
            short8 a = *(const short8*)(sXH + hbase + (dy * 226 + dxx + c16) * 16 + c0);
#pragma unroll
            for (int nt = 0; nt < 8; ++nt) acc[nt] = MFMA16(a, wf[kc][nt], acc[nt]);
          }
          short* dst = sBUF + ((j & 1) * 2 + wv) * 2176;
#pragma unroll
          for (int r = 0; r < 4; ++r) {
            uint4v pk;
#pragma unroll
            for (int h = 0; h < 4; ++h) {
              float v0 = acc[2 * h][r]     + ((2 * h < 4) ? bA[2 * h]     : bB[2 * h - 4]);
              float v1 = acc[2 * h + 1][r] + ((2 * h + 1 < 4) ? bA[2 * h + 1] : bB[2 * h - 3]);
              pk[h] = pk2bf(fmaxf(v0, 0.f), fmaxf(v1, 0.f));
            }
            *(short8*)(dst + (q * 4 + r) * 136 + c16 * 8) = __builtin_bit_cast(short8, pk);
          }
        }
        sync_lds();
      }
    } else {
      // ========= G23 waves: MLP2 (tile j-1) + MLP3/update (tile j-2) ====
      const int g = wv - 2;
      for (int j = 0; j < 16; ++j) {
        float xres[4];
        int cb3 = 0, hglob3 = 0;
        if (j >= 2) {                   // prefetch residual x
          const int t3 = 2 * (j - 2) + g;
          cb3 = (t3 % 14) * 16; hglob3 = h0 + t3 / 14;
#pragma unroll
          for (int r = 0; r < 4; ++r) {
            size_t pix = (size_t)(b * 224 + hglob3) * 224 + cb3 + q * 4 + r;
            xres[r] = xs32[pix * 16 + c16];
          }
        }
        if (j >= 1 && j <= 14) {        // G2: mailbox -> h2 dbuf
          const short* src = sBUF + (((j - 1) & 1) * 2 + g) * 2176;
          float4v acc2[8];
#pragma unroll
          for (int nt = 0; nt < 8; ++nt) acc2[nt] = (float4v){0.f, 0.f, 0.f, 0.f};
#pragma unroll
          for (int kc = 0; kc < 4; ++kc) {
            short8 a = *(const short8*)(src + c16 * 136 + kc * 32 + q8);
#pragma unroll
            for (int nt = 0; nt < 8; ++nt) acc2[nt] = MFMA16(a, w2f[kc][nt], acc2[nt]);
          }
          short* dsth2 = sH2 + ((j & 1) * 2 + g) * 2176;
#pragma unroll
          for (int r = 0; r < 4; ++r) {
            uint4v pk;
#pragma unroll
            for (int h = 0; h < 4; ++h) {
              float v0 = acc2[2 * h][r]     + ((2 * h < 4) ? bA[2 * h]     : bB[2 * h - 4]);
              float v1 = acc2[2 * h + 1][r] + ((2 * h + 1 < 4) ? bA[2 * h + 1] : bB[2 * h - 3]);
              pk[h] = pk2bf(fmaxf(v0, 0.f), fmaxf(v1, 0.f));
            }
            *(short8*)(dsth2 + (q * 4 + r) * 136 + c16 * 8) = __builtin_bit_cast(short8, pk);
          }
        }
        if (j >= 2) {                   // G3 + epilogue on h2 from last iter
          const short* srch2 = sH2 + ((((j - 1) & 1)) * 2 + g) * 2176;
          float4v acc3 = (float4v){0.f, 0.f, 0.f, 0.f};
#pragma unroll
          for (int kc = 0; kc < 4; ++kc) {
            short8 a = *(const short8*)(srch2 + c16 * 136 + kc * 32 + q8);
            acc3 = MFMA16(a, w3f[kc], acc3);
          }
#pragma unroll
          for (int r = 0; r < 4; ++r) {
            int col = cb3 + q * 4 + r;
            size_t pix = (size_t)(b * 224 + hglob3) * 224 + col;
            float v = xres[r] + acc3[r];
            v = fminf(fmaxf(v, 0.f), 1.f);
            if (last) {
              dout[((size_t)(b * 16 + c16) * 224 + hglob3) * 224 + col] = v;
            } else {
              xd32[pix * 16 + c16] = v;
              xd16[pix * 16 + c16] = f2bf(v);
            }
          }
        }
        sync_lds();
      }
    }

    __syncthreads();                    // all waves' stores drained (vmcnt 0)

    if (tid == 0 && !last) {            // publish state version s+1
      __builtin_amdgcn_fence(__ATOMIC_RELEASE, "agent");
      __hip_atomic_store(&done[blk], (unsigned)(s + 1), __ATOMIC_RELAXED,
                         __HIP_MEMORY_SCOPE_AGENT);
    }
  }
}

// ---------------------------------------------------------------------------
extern "C" void kernel_launch(void* const* d_in, const int* in_sizes, int n_in,
                              void* d_out, int out_size, void* d_ws, size_t ws_size,
                              hipStream_t stream) {
  const float* x  = (const float*)d_in[0];
  const float* wp = (const float*)d_in[1];
  const float* w1 = (const float*)d_in[2];
  const float* b1 = (const float*)d_in[3];
  const float* w2 = (const float*)d_in[4];
  const float* b2 = (const float*)d_in[5];
  const float* w3 = (const float*)d_in[6];

  char* ws = (char*)d_ws;
  short* wEg = (short*)(ws + WS_WE);
  short* w2g = (short*)(ws + WS_W2);
  short* w3g = (short*)(ws + WS_W3);
  float* b1p = (float*)(ws + WS_B1);
  float* b2p = (float*)(ws + WS_B2);
  float* X32a = (float*)(ws + WS_X32A);
  float* X32b = (float*)(ws + WS_X32B);
  short* X16a = (short*)(ws + WS_X16A);
  short* X16b = (short*)(ws + WS_X16B);
  unsigned* done = (unsigned*)(ws + WS_DONE);

  prep_x<<<12544, 256, 0, stream>>>(x, X32a, X16a, done);
  prep_w<<<163, 256, 0, stream>>>(wp, w1, b1, w2, b2, w3, wEg, w2g, w3g, b1p, b2p);

  ca_persist<<<448, 256, 0, stream>>>(wEg, w2g, w3g, b1p, b2p,
                                      X32a, X16a, X32b, X16b,
                                      (float*)d_out, done);
}

// Round 6
// 1420.384 us; speedup vs baseline: 3.5153x; 3.5153x over previous
//
#include <hip/hip_runtime.h>

// ---------------------------------------------------------------------------
// NeuralCA, persistent kernel v2: all 40 steps in ONE launch.
//   Role loops are branch-local so wf[] and w2f[]/w3f[] live ranges are
//   DISJOINT in the CFG (R5 hoisted both -> 304 VGPR overlap -> demotion to
//   memory, 4.5x regression). Weight frags pinned with empty asm to block
//   rematerialization inside the step loop.
//   Block = 2 image rows (448 blocks, 2/CU, 63.7KB LDS).
//   waves 0-1 (G1):  h1 = relu(W_eff * im2col(x) + b1)   W_eff regs 160 VGPR
//   waves 2-3 (G23): G2 on h1[j-1] -> h2 dbuf; G3+epilogue on h2[j-2]
//   Steps ordered by neighbor-only flag sync (done[blk] = state version,
//   agent-scope release/acquire). Identical barrier sequence in both branches.
// ---------------------------------------------------------------------------

typedef __attribute__((ext_vector_type(8))) short short8;
typedef __attribute__((ext_vector_type(4))) float float4v;
typedef __attribute__((ext_vector_type(4))) unsigned uint4v;

#define MFMA16(a, b, c) __builtin_amdgcn_mfma_f32_16x16x32_bf16((a), (b), (c), 0, 0, 0)

// pin a 16B fragment into VGPRs; opaque to remat/CSE
#define PIN4(x) asm volatile("" : "+v"(x))

__device__ __forceinline__ short f2bf(float f) {
  unsigned u = __builtin_bit_cast(unsigned, f);
  return (short)((u + 0x8000u) >> 16);     // round-half-up
}

__device__ __forceinline__ unsigned pk2bf(float a, float b) {
  unsigned ua = __builtin_bit_cast(unsigned, a), ub = __builtin_bit_cast(unsigned, b);
  return ((ua + 0x8000u) >> 16) | (((ub + 0x8000u) >> 16) << 16);
}

__device__ __forceinline__ void async16(const void* g, void* l) {
  __builtin_amdgcn_global_load_lds((const __attribute__((address_space(1))) void*)g,
                                   (__attribute__((address_space(3))) void*)l,
                                   16, 0, 0);
}

// LDS-only barrier (no vmcnt drain)
__device__ __forceinline__ void sync_lds() {
  asm volatile("s_waitcnt lgkmcnt(0)\n\ts_barrier" ::: "memory");
}
// full barrier: drain own vm+lgkm then barrier
__device__ __forceinline__ void barrier_full() {
  asm volatile("s_waitcnt vmcnt(0) lgkmcnt(0)\n\ts_barrier" ::: "memory");
}

// ---- workspace layout (bytes) ----
#define WS_WE    0          // W_eff^T [128][168] bf16 (K pad 144->168, zeros)
#define WS_W2    43008      // W2^T    [128][136] bf16 (K sigma-permuted)
#define WS_W3    77824      // W3^T    [ 16][136] bf16 (sigma-perm, pad 2560)
#define WS_B1    82944      // b1 sigma-permuted f32 [128]
#define WS_B2    83456      // b2 sigma-permuted f32 [128]
#define WS_X32A  83968
#define WS_X32B  12929024
#define WS_X16A  25774080
#define WS_X16B  32196608
#define WS_DONE  38619136   // unsigned done[512]

// ---------------------------------------------------------------------------
__global__ void prep_x(const float* __restrict__ x, float* __restrict__ x32,
                       short* __restrict__ x16, unsigned* __restrict__ done) {
  if (blockIdx.x < 2) done[blockIdx.x * 256 + threadIdx.x] = 0;  // sync flags
  int i = blockIdx.x * 256 + threadIdx.x;          // exactly 3211264 threads
  int w = i % 224;
  int h = (i / 224) % 224;
  int c = (i / 50176) & 15;
  int bb = i / 802816;
  float v = x[i];
  int o = ((bb * 224 + h) * 224 + w) * 16 + c;     // NHWC
  x32[o] = v;
  x16[o] = f2bf(v);
}

// sigma: stored position p holds channel chan(p) = 16*(p&7) + (p>>3)
__global__ void prep_w(const float* __restrict__ wp, const float* __restrict__ w1,
                       const float* __restrict__ b1, const float* __restrict__ w2,
                       const float* __restrict__ b2, const float* __restrict__ w3,
                       short* __restrict__ wE, short* __restrict__ w2t,
                       short* __restrict__ w3t, float* __restrict__ b1p,
                       float* __restrict__ b2p) {
  int i = blockIdx.x * 256 + threadIdx.x;          // exactly 41728 threads
  if (i < 21504) {                                  // W_eff^T [o=128][k=168]
    int o = i / 168, k = i % 168;
    float v = 0.f;
    if (k < 144) {
      int off = k >> 4, c = k & 15;                 // k = offset*16 + c
      for (int c3 = 0; c3 < 48; ++c3)
        v += w1[o * 48 + c3] * wp[c3 * 144 + c * 9 + off];
    }
    wE[i] = f2bf(v);
  } else if (i < 38912) {                           // W2^T perm [n=128][kk=136]
    int j = i - 21504;
    int n = j / 136, kk = j % 136;
    float v = 0.f;
    if (kk < 128) { int ch = 16 * (kk & 7) + (kk >> 3); v = w2[n * 128 + ch]; }
    w2t[j] = f2bf(v);
  } else if (i < 41472) {                           // W3^T perm, padded to 2560
    int j = i - 38912;
    float v = 0.f;
    if (j < 2176) {
      int n = j / 136, kk = j % 136;
      if (kk < 128) { int ch = 16 * (kk & 7) + (kk >> 3); v = w3[n * 128 + ch]; }
    }
    w3t[j] = f2bf(v);
  } else if (i < 41600) {
    int p = i - 41472;
    b1p[p] = b1[16 * (p & 7) + (p >> 3)];
  } else {
    int p = i - 41600;
    b2p[p] = b2[16 * (p & 7) + (p >> 3)];
  }
}

// ---------------------------------------------------------------------------
__global__ __launch_bounds__(256, 2) void ca_persist(
    const short* __restrict__ wEg, const short* __restrict__ w2g,
    const short* __restrict__ w3g, const float* __restrict__ b1p,
    const float* __restrict__ b2p, float* __restrict__ X32a,
    short* __restrict__ X16a, float* __restrict__ X32b,
    short* __restrict__ X16b, float* __restrict__ dout,
    unsigned* __restrict__ done) {
  __shared__ short sXH[4 * 3616];       // 28928 B  halo: 4 rows x 226 x 16ch
  __shared__ short sBUF[2 * 2 * 2176];  // 17408 B  h1 mailbox dbuf
  __shared__ short sH2[2 * 2 * 2176];   // 17408 B  h2 dbuf
  // total 63744 B -> 2 blocks/CU; 448 blocks <= 512 capacity (co-resident)

  const int tid = threadIdx.x;
  const int lane = tid & 63;
  const int wv = tid >> 6;
  const int c16 = lane & 15;
  const int q = lane >> 4;
  const int q8 = q * 8;
  const int qh = q >> 1;
  const int c0 = (q & 1) * 8;

  const int blk = blockIdx.x;           // 448 = 4 batches x 112 rowgroups
  const int b = blk / 112;
  const int rg = blk % 112;
  const int h0 = rg * 2;
  const bool hasUp = rg > 0, hasDn = rg < 111;

  const short8 z8 = {0, 0, 0, 0, 0, 0, 0, 0};
  if (tid < 16) {   // zero edge cols (image col -1 and 224) once; staging
    int hr = tid >> 2, wch = tid & 3;   // never touches them
    int colb = (wch < 2) ? 0 : 225;
    *(short8*)((char*)sXH + hr * 7232 + colb * 32 + (wch & 1) * 16) = z8;
  }

  if (wv < 2) {
    // =================== G1 role: conv3x3+MLP1 fused =====================
    short8 wf[5][8];                    // 160 VGPR, branch-local live range
#pragma unroll
    for (int kc = 0; kc < 5; ++kc)
#pragma unroll
      for (int nt = 0; nt < 8; ++nt) {
        uint4v t = __builtin_bit_cast(uint4v,
            *(const short8*)(wEg + (nt * 16 + c16) * 168 + kc * 32 + q8));
        PIN4(t);
        wf[kc][nt] = __builtin_bit_cast(short8, t);
      }
    const float4v bA = *(const float4v*)(b1p + c16 * 8);
    const float4v bB = *(const float4v*)(b1p + c16 * 8 + 4);

    for (int s = 0; s < 40; ++s) {
      const short* xs16 = (s & 1) ? X16b : X16a;
      if (tid == 0 && s > 0) {          // wait for neighbors @ version s
        if (hasUp)
          while (__hip_atomic_load(&done[blk - 1], __ATOMIC_RELAXED,
                                   __HIP_MEMORY_SCOPE_AGENT) < (unsigned)s)
            asm volatile("s_sleep 2");
        if (hasDn)
          while (__hip_atomic_load(&done[blk + 1], __ATOMIC_RELAXED,
                                   __HIP_MEMORY_SCOPE_AGENT) < (unsigned)s)
            asm volatile("s_sleep 2");
        __builtin_amdgcn_fence(__ATOMIC_ACQUIRE, "agent");
      }
      barrier_full();                   // [A]
      for (int t = wv; t < 28; t += 4) {  // stage halo rows
        int hr = t / 7, ck = t % 7;
        int hh = h0 - 1 + hr;
        char* l = (char*)sXH + hr * 7232 + 32 + ck * 1024;
        if (hh >= 0 && hh < 224) {
          const char* g = (const char*)xs16 + ((size_t)(b * 224 + hh) * 224) * 32 + ck * 1024;
          async16(g + lane * 16, l);
        } else {
          *(short8*)(l + lane * 16) = z8;
        }
      }
      barrier_full();                   // [B] halo ready

      for (int j = 0; j < 16; ++j) {
        if (j < 14) {
          const int t = 2 * j + wv;
          const int rr = t / 14, cb = (t % 14) * 16;
          const int hbase = (rr * 226 + cb) * 16;
          float4v acc[8];
#pragma unroll
          for (int nt = 0; nt < 8; ++nt) acc[nt] = (float4v){0.f, 0.f, 0.f, 0.f};
#pragma unroll
          for (int kc = 0; kc < 5; ++kc) {
            int off = kc * 2 + qh;
            if (off > 8) off = 8;       // K 144..159 hit zero rows of W_eff
            int dy = (off * 11) >> 5;   // off/3
            int dxx = off - dy * 3;
            short8 a = *(const short8*)(sXH + hbase + (dy * 226 + dxx + c16) * 16 + c0);
#pragma unroll
            for (int nt = 0; nt < 8; ++nt) acc[nt] = MFMA16(a, wf[kc][nt], acc[nt]);
          }
          short* dst = sBUF + ((j & 1) * 2 + wv) * 2176;
#pragma unroll
          for (int r = 0; r < 4; ++r) {
            uint4v pk;
#pragma unroll
            for (int h = 0; h < 4; ++h) {
              float v0 = acc[2 * h][r]     + ((2 * h < 4) ? bA[2 * h]     : bB[2 * h - 4]);
              float v1 = acc[2 * h + 1][r] + ((2 * h + 1 < 4) ? bA[2 * h + 1] : bB[2 * h - 3]);
              pk[h] = pk2bf(fmaxf(v0, 0.f), fmaxf(v1, 0.f));
            }
            *(short8*)(dst + (q * 4 + r) * 136 + c16 * 8) = __builtin_bit_cast(short8, pk);
          }
        }
        sync_lds();                     // [1..16]
      }
      barrier_full();                   // [C] (G1 has no global stores)
      if (tid == 0 && s < 39) {         // publish version s+1
        __builtin_amdgcn_fence(__ATOMIC_RELEASE, "agent");
        __hip_atomic_store(&done[blk], (unsigned)(s + 1), __ATOMIC_RELAXED,
                           __HIP_MEMORY_SCOPE_AGENT);
      }
    }
  } else {
    // ====== G23 role: MLP2 (tile j-1) + MLP3/update (tile j-2) ===========
    short8 w2f[4][8];                   // 128 VGPR, branch-local
    short8 w3f[4];                      //  16 VGPR
#pragma unroll
    for (int kc = 0; kc < 4; ++kc)
#pragma unroll
      for (int nt = 0; nt < 8; ++nt) {
        uint4v t = __builtin_bit_cast(uint4v,
            *(const short8*)(w2g + (nt * 16 + c16) * 136 + kc * 32 + q8));
        PIN4(t);
        w2f[kc][nt] = __builtin_bit_cast(short8, t);
      }
#pragma unroll
    for (int kc = 0; kc < 4; ++kc) {
      uint4v t = __builtin_bit_cast(uint4v,
          *(const short8*)(w3g + c16 * 136 + kc * 32 + q8));
      PIN4(t);
      w3f[kc] = __builtin_bit_cast(short8, t);
    }
    const float4v bA = *(const float4v*)(b2p + c16 * 8);
    const float4v bB = *(const float4v*)(b2p + c16 * 8 + 4);
    const int g = wv - 2;

    for (int s = 0; s < 40; ++s) {
      const int sb = s & 1;
      const float* xs32 = sb ? X32b : X32a;
      const short* xs16 = sb ? X16b : X16a;
      float* xd32 = sb ? X32a : X32b;
      short* xd16 = sb ? X16a : X16b;
      const bool last = (s == 39);

      barrier_full();                   // [A] (wait happens in G1's tid0)
      for (int t = wv; t < 28; t += 4) {  // stage halo rows (wv in {2,3})
        int hr = t / 7, ck = t % 7;
        int hh = h0 - 1 + hr;
        char* l = (char*)sXH + hr * 7232 + 32 + ck * 1024;
        if (hh >= 0 && hh < 224) {
          const char* g2 = (const char*)xs16 + ((size_t)(b * 224 + hh) * 224) * 32 + ck * 1024;
          async16(g2 + lane * 16, l);
        } else {
          *(short8*)(l + lane * 16) = z8;
        }
      }
      barrier_full();                   // [B] halo ready

      for (int j = 0; j < 16; ++j) {
        float xres[4];
        int cb3 = 0, hglob3 = 0;
        if (j >= 2) {                   // prefetch residual x
          const int t3 = 2 * (j - 2) + g;
          cb3 = (t3 % 14) * 16; hglob3 = h0 + t3 / 14;
#pragma unroll
          for (int r = 0; r < 4; ++r) {
            size_t pix = (size_t)(b * 224 + hglob3) * 224 + cb3 + q * 4 + r;
            xres[r] = xs32[pix * 16 + c16];
          }
        }
        if (j >= 1 && j <= 14) {        // G2: mailbox -> h2 dbuf
          const short* src = sBUF + (((j - 1) & 1) * 2 + g) * 2176;
          float4v acc2[8];
#pragma unroll
          for (int nt = 0; nt < 8; ++nt) acc2[nt] = (float4v){0.f, 0.f, 0.f, 0.f};
#pragma unroll
          for (int kc = 0; kc < 4; ++kc) {
            short8 a = *(const short8*)(src + c16 * 136 + kc * 32 + q8);
#pragma unroll
            for (int nt = 0; nt < 8; ++nt) acc2[nt] = MFMA16(a, w2f[kc][nt], acc2[nt]);
          }
          short* dsth2 = sH2 + ((j & 1) * 2 + g) * 2176;
#pragma unroll
          for (int r = 0; r < 4; ++r) {
            uint4v pk;
#pragma unroll
            for (int h = 0; h < 4; ++h) {
              float v0 = acc2[2 * h][r]     + ((2 * h < 4) ? bA[2 * h]     : bB[2 * h - 4]);
              float v1 = acc2[2 * h + 1][r] + ((2 * h + 1 < 4) ? bA[2 * h + 1] : bB[2 * h - 3]);
              pk[h] = pk2bf(fmaxf(v0, 0.f), fmaxf(v1, 0.f));
            }
            *(short8*)(dsth2 + (q * 4 + r) * 136 + c16 * 8) = __builtin_bit_cast(short8, pk);
          }
        }
        if (j >= 2) {                   // G3 + epilogue on h2 from last iter
          const short* srch2 = sH2 + ((((j - 1) & 1)) * 2 + g) * 2176;
          float4v acc3 = (float4v){0.f, 0.f, 0.f, 0.f};
#pragma unroll
          for (int kc = 0; kc < 4; ++kc) {
            short8 a = *(const short8*)(srch2 + c16 * 136 + kc * 32 + q8);
            acc3 = MFMA16(a, w3f[kc], acc3);
          }
#pragma unroll
          for (int r = 0; r < 4; ++r) {
            int col = cb3 + q * 4 + r;
            size_t pix = (size_t)(b * 224 + hglob3) * 224 + col;
            float v = xres[r] + acc3[r];
            v = fminf(fmaxf(v, 0.f), 1.f);
            if (last) {
              dout[((size_t)(b * 16 + c16) * 224 + hglob3) * 224 + col] = v;
            } else {
              xd32[pix * 16 + c16] = v;
              xd16[pix * 16 + c16] = f2bf(v);
            }
          }
        }
        sync_lds();                     // [1..16]
      }
      barrier_full();                   // [C] epilogue stores drained
      // publish is done by tid0 (G1 branch)
    }
  }
}

// ---------------------------------------------------------------------------
extern "C" void kernel_launch(void* const* d_in, const int* in_sizes, int n_in,
                              void* d_out, int out_size, void* d_ws, size_t ws_size,
                              hipStream_t stream) {
  const float* x  = (const float*)d_in[0];
  const float* wp = (const float*)d_in[1];
  const float* w1 = (const float*)d_in[2];
  const float* b1 = (const float*)d_in[3];
  const float* w2 = (const float*)d_in[4];
  const float* b2 = (const float*)d_in[5];
  const float* w3 = (const float*)d_in[6];

  char* ws = (char*)d_ws;
  short* wEg = (short*)(ws + WS_WE);
  short* w2g = (short*)(ws + WS_W2);
  short* w3g = (short*)(ws + WS_W3);
  float* b1p = (float*)(ws + WS_B1);
  float* b2p = (float*)(ws + WS_B2);
  float* X32a = (float*)(ws + WS_X32A);
  float* X32b = (float*)(ws + WS_X32B);
  short* X16a = (short*)(ws + WS_X16A);
  short* X16b = (short*)(ws + WS_X16B);
  unsigned* done = (unsigned*)(ws + WS_DONE);

  prep_x<<<12544, 256, 0, stream>>>(x, X32a, X16a, done);
  prep_w<<<163, 256, 0, stream>>>(wp, w1, b1, w2, b2, w3, wEg, w2g, w3g, b1p, b2p);

  ca_persist<<<448, 256, 0, stream>>>(wEg, w2g, w3g, b1p, b2p,
                                      X32a, X16a, X32b, X16b,
                                      (float*)d_out, done);
}

// Round 7
// 1414.900 us; speedup vs baseline: 3.5290x; 1.0039x over previous
//
#include <hip/hip_runtime.h>

// ---------------------------------------------------------------------------
// NeuralCA, persistent kernel v3: all 40 steps in ONE launch, N-split weights.
//   R6 failed because G1's weight array (160 VGPR) + working set sat at the
//   256-VGPR cap -> allocator demoted weights to memory -> L2-BW-bound
//   (~27 TB/s weight re-fetch). v3 halves per-wave weight footprint by
//   splitting the N dimension across the two waves of each role:
//     waves 0-1 (G1, half H):  20 W_eff frags (80 VGPR), 2 tiles/iter
//     waves 2-3 (G23, half g): 16 W2 frags (64 VGPR) + 4 W3 frags,
//                              G2 half-N for 2 tiles; G3 full-K for 1 tile
//                              one iter later (h2 halves merged via dbuf+barrier)
//   Block = 2 image rows, 448 blocks, 2/CU (63.7 KB LDS), neighbor flag sync.
// ---------------------------------------------------------------------------

typedef __attribute__((ext_vector_type(8))) short short8;
typedef __attribute__((ext_vector_type(4))) float float4v;
typedef __attribute__((ext_vector_type(2))) unsigned uint2v;

#define MFMA16(a, b, c) __builtin_amdgcn_mfma_f32_16x16x32_bf16((a), (b), (c), 0, 0, 0)

__device__ __forceinline__ short f2bf(float f) {
  unsigned u = __builtin_bit_cast(unsigned, f);
  return (short)((u + 0x8000u) >> 16);     // round-half-up
}

__device__ __forceinline__ unsigned pk2bf(float a, float b) {
#if __has_builtin(__builtin_amdgcn_cvt_pk_bf16_f32)
  typedef __attribute__((ext_vector_type(2))) __bf16 bf2;
  bf2 r = __builtin_amdgcn_cvt_pk_bf16_f32(a, b);
  return __builtin_bit_cast(unsigned, r);
#else
  unsigned ua = __builtin_bit_cast(unsigned, a), ub = __builtin_bit_cast(unsigned, b);
  return ((ua + 0x8000u) >> 16) | (((ub + 0x8000u) >> 16) << 16);
#endif
}

__device__ __forceinline__ void async16(const void* g, void* l) {
  __builtin_amdgcn_global_load_lds((const __attribute__((address_space(1))) void*)g,
                                   (__attribute__((address_space(3))) void*)l,
                                   16, 0, 0);
}

// LDS-only barrier (no vmcnt drain)
__device__ __forceinline__ void sync_lds() {
  asm volatile("s_waitcnt lgkmcnt(0)\n\ts_barrier" ::: "memory");
}
// full barrier: drain own vm+lgkm then barrier
__device__ __forceinline__ void barrier_full() {
  asm volatile("s_waitcnt vmcnt(0) lgkmcnt(0)\n\ts_barrier" ::: "memory");
}

// ---- workspace layout (bytes) ----
#define WS_WE    0          // W_eff^T [128][168] bf16 (K pad 144->168, zeros)
#define WS_W2    43008      // W2^T    [128][136] bf16 (K sigma-permuted)
#define WS_W3    77824      // W3^T    [ 16][136] bf16 (sigma-perm, pad 2560)
#define WS_B1    82944      // b1 sigma-permuted f32 [128]
#define WS_B2    83456      // b2 sigma-permuted f32 [128]
#define WS_X32A  83968
#define WS_X32B  12929024
#define WS_X16A  25774080
#define WS_X16B  32196608
#define WS_DONE  38619136   // unsigned done[512]

// ---------------------------------------------------------------------------
__global__ void prep_x(const float* __restrict__ x, float* __restrict__ x32,
                       short* __restrict__ x16, unsigned* __restrict__ done) {
  if (blockIdx.x < 2) done[blockIdx.x * 256 + threadIdx.x] = 0;  // sync flags
  int i = blockIdx.x * 256 + threadIdx.x;          // exactly 3211264 threads
  int w = i % 224;
  int h = (i / 224) % 224;
  int c = (i / 50176) & 15;
  int bb = i / 802816;
  float v = x[i];
  int o = ((bb * 224 + h) * 224 + w) * 16 + c;     // NHWC
  x32[o] = v;
  x16[o] = f2bf(v);
}

// sigma: stored position p holds channel chan(p) = 16*(p&7) + (p>>3)
__global__ void prep_w(const float* __restrict__ wp, const float* __restrict__ w1,
                       const float* __restrict__ b1, const float* __restrict__ w2,
                       const float* __restrict__ b2, const float* __restrict__ w3,
                       short* __restrict__ wE, short* __restrict__ w2t,
                       short* __restrict__ w3t, float* __restrict__ b1p,
                       float* __restrict__ b2p) {
  int i = blockIdx.x * 256 + threadIdx.x;          // exactly 41728 threads
  if (i < 21504) {                                  // W_eff^T [o=128][k=168]
    int o = i / 168, k = i % 168;
    float v = 0.f;
    if (k < 144) {
      int off = k >> 4, c = k & 15;                 // k = offset*16 + c
      for (int c3 = 0; c3 < 48; ++c3)
        v += w1[o * 48 + c3] * wp[c3 * 144 + c * 9 + off];
    }
    wE[i] = f2bf(v);
  } else if (i < 38912) {                           // W2^T perm [n=128][kk=136]
    int j = i - 21504;
    int n = j / 136, kk = j % 136;
    float v = 0.f;
    if (kk < 128) { int ch = 16 * (kk & 7) + (kk >> 3); v = w2[n * 128 + ch]; }
    w2t[j] = f2bf(v);
  } else if (i < 41472) {                           // W3^T perm, padded to 2560
    int j = i - 38912;
    float v = 0.f;
    if (j < 2176) {
      int n = j / 136, kk = j % 136;
      if (kk < 128) { int ch = 16 * (kk & 7) + (kk >> 3); v = w3[n * 128 + ch]; }
    }
    w3t[j] = f2bf(v);
  } else if (i < 41600) {
    int p = i - 41472;
    b1p[p] = b1[16 * (p & 7) + (p >> 3)];
  } else {
    int p = i - 41600;
    b2p[p] = b2[16 * (p & 7) + (p >> 3)];
  }
}

// ---------------------------------------------------------------------------
// Pipeline (16 iters/step, 28 tiles of 16 px per 2-row block):
//   G1 wave H:  iter j<14:     h1 halves of tiles {2j, 2j+1} -> sBUF slot j&1
//   G23 wave g: iter 1<=j<=14: G2 halves of tiles {2(j-1), 2(j-1)+1} -> sH2 j&1
//               iter j>=2:     G3 full-K + epilogue of tile 2(j-2)+g
__global__ __launch_bounds__(256, 2) void ca_persist(
    const short* __restrict__ wEg, const short* __restrict__ w2g,
    const short* __restrict__ w3g, const float* __restrict__ b1p,
    const float* __restrict__ b2p, float* __restrict__ X32a,
    short* __restrict__ X16a, float* __restrict__ X32b,
    short* __restrict__ X16b, float* __restrict__ dout,
    unsigned* __restrict__ done) {
  __shared__ short sXH[4 * 3616];       // 28928 B  halo: 4 rows x 226 x 16ch
  __shared__ short sBUF[2 * 2 * 2176];  // 17408 B  h1 mailbox dbuf x 2 tiles
  __shared__ short sH2[2 * 2 * 2176];   // 17408 B  h2 dbuf x 2 tiles
  // total 63744 B -> 2 blocks/CU; 448 blocks <= 512 capacity (co-resident)

  const int tid = threadIdx.x;
  const int lane = tid & 63;
  const int wv = tid >> 6;
  const int c16 = lane & 15;
  const int q = lane >> 4;
  const int q8 = q * 8;
  const int qh = q >> 1;
  const int c0 = (q & 1) * 8;

  const int blk = blockIdx.x;           // 448 = 4 batches x 112 rowgroups
  const int b = blk / 112;
  const int rg = blk % 112;
  const int h0 = rg * 2;
  const bool hasUp = rg > 0, hasDn = rg < 111;

  const short8 z8 = {0, 0, 0, 0, 0, 0, 0, 0};
  if (tid < 16) {   // zero edge cols (image col -1 and 224) once
    int hr = tid >> 2, wch = tid & 3;
    int colb = (wch < 2) ? 0 : 225;
    *(short8*)((char*)sXH + hr * 7232 + colb * 32 + (wch & 1) * 16) = z8;
  }

  if (wv < 2) {
    // ============ G1 role, N-half H: conv3x3+MLP1 fused ==================
    const int H = wv;
    short8 wf[5][4];                    // 80 VGPR
#pragma unroll
    for (int kc = 0; kc < 5; ++kc)
#pragma unroll
      for (int n = 0; n < 4; ++n)
        wf[kc][n] = *(const short8*)(wEg + ((H * 4 + n) * 16 + c16) * 168 + kc * 32 + q8);
    const float4v bH = *(const float4v*)(b1p + c16 * 8 + H * 4);

    for (int s = 0; s < 40; ++s) {
      const short* xs16 = (s & 1) ? X16b : X16a;
      if (tid == 0 && s > 0) {          // wait for neighbors @ version s
        if (hasUp)
          while (__hip_atomic_load(&done[blk - 1], __ATOMIC_RELAXED,
                                   __HIP_MEMORY_SCOPE_AGENT) < (unsigned)s)
            asm volatile("s_sleep 2");
        if (hasDn)
          while (__hip_atomic_load(&done[blk + 1], __ATOMIC_RELAXED,
                                   __HIP_MEMORY_SCOPE_AGENT) < (unsigned)s)
            asm volatile("s_sleep 2");
        __builtin_amdgcn_fence(__ATOMIC_ACQUIRE, "agent");
      }
      barrier_full();                   // [A]
      for (int t = wv; t < 28; t += 4) {  // stage halo rows
        int hr = t / 7, ck = t % 7;
        int hh = h0 - 1 + hr;
        char* l = (char*)sXH + hr * 7232 + 32 + ck * 1024;
        if (hh >= 0 && hh < 224) {
          const char* g = (const char*)xs16 + ((size_t)(b * 224 + hh) * 224) * 32 + ck * 1024;
          async16(g + lane * 16, l);
        } else {
          *(short8*)(l + lane * 16) = z8;
        }
      }
      barrier_full();                   // [B] halo ready

      for (int j = 0; j < 16; ++j) {
        if (j < 14) {
          const int t0 = 2 * j, t1 = t0 + 1;
          const int hb0 = ((t0 / 14) * 226 + (t0 % 14) * 16) * 16;
          const int hb1 = ((t1 / 14) * 226 + (t1 % 14) * 16) * 16;
          float4v acc[2][4];
#pragma unroll
          for (int tt = 0; tt < 2; ++tt)
#pragma unroll
            for (int n = 0; n < 4; ++n) acc[tt][n] = (float4v){0.f, 0.f, 0.f, 0.f};
#pragma unroll
          for (int kc = 0; kc < 5; ++kc) {
            int off = kc * 2 + qh;
            if (off > 8) off = 8;       // K 144..159 hit zero rows of W_eff
            int dy = (off * 11) >> 5;   // off/3
            int dxx = off - dy * 3;
            const int ao = (dy * 226 + dxx + c16) * 16 + c0;
            short8 a0 = *(const short8*)(sXH + hb0 + ao);
            short8 a1 = *(const short8*)(sXH + hb1 + ao);
#pragma unroll
            for (int n = 0; n < 4; ++n) {
              acc[0][n] = MFMA16(a0, wf[kc][n], acc[0][n]);
              acc[1][n] = MFMA16(a1, wf[kc][n], acc[1][n]);
            }
          }
#pragma unroll
          for (int tt = 0; tt < 2; ++tt) {
            short* dst = sBUF + ((j & 1) * 2 + tt) * 2176;
#pragma unroll
            for (int r = 0; r < 4; ++r) {
              uint2v pk;
              pk[0] = pk2bf(fmaxf(acc[tt][0][r] + bH[0], 0.f),
                            fmaxf(acc[tt][1][r] + bH[1], 0.f));
              pk[1] = pk2bf(fmaxf(acc[tt][2][r] + bH[2], 0.f),
                            fmaxf(acc[tt][3][r] + bH[3], 0.f));
              *(uint2v*)(dst + (q * 4 + r) * 136 + c16 * 8 + H * 4) = pk;
            }
          }
        }
        sync_lds();                     // [1..16]
      }
      barrier_full();                   // [C]
      if (tid == 0 && s < 39) {         // publish version s+1
        __builtin_amdgcn_fence(__ATOMIC_RELEASE, "agent");
        __hip_atomic_store(&done[blk], (unsigned)(s + 1), __ATOMIC_RELAXED,
                           __HIP_MEMORY_SCOPE_AGENT);
      }
    }
  } else {
    // ====== G23 role, N-half g: MLP2 halves + full MLP3/update ===========
    const int g = wv - 2;
    short8 w2f[4][4];                   // 64 VGPR
    short8 w3f[4];                      // 16 VGPR
#pragma unroll
    for (int kc = 0; kc < 4; ++kc)
#pragma unroll
      for (int n = 0; n < 4; ++n)
        w2f[kc][n] = *(const short8*)(w2g + ((g * 4 + n) * 16 + c16) * 136 + kc * 32 + q8);
#pragma unroll
    for (int kc = 0; kc < 4; ++kc)
      w3f[kc] = *(const short8*)(w3g + c16 * 136 + kc * 32 + q8);
    const float4v bG = *(const float4v*)(b2p + c16 * 8 + g * 4);

    for (int s = 0; s < 40; ++s) {
      const int sb = s & 1;
      const float* xs32 = sb ? X32b : X32a;
      const short* xs16 = sb ? X16b : X16a;
      float* xd32 = sb ? X32a : X32b;
      short* xd16 = sb ? X16a : X16b;
      const bool last = (s == 39);

      barrier_full();                   // [A] (neighbor wait runs in tid0)
      for (int t = wv; t < 28; t += 4) {  // stage halo rows
        int hr = t / 7, ck = t % 7;
        int hh = h0 - 1 + hr;
        char* l = (char*)sXH + hr * 7232 + 32 + ck * 1024;
        if (hh >= 0 && hh < 224) {
          const char* g2 = (const char*)xs16 + ((size_t)(b * 224 + hh) * 224) * 32 + ck * 1024;
          async16(g2 + lane * 16, l);
        } else {
          *(short8*)(l + lane * 16) = z8;
        }
      }
      barrier_full();                   // [B] halo ready

      for (int j = 0; j < 16; ++j) {
        float xres[4];
        int cb3 = 0, hglob3 = 0;
        if (j >= 2) {                   // prefetch residual x for G3's tile
          const int t3 = 2 * (j - 2) + g;
          cb3 = (t3 % 14) * 16; hglob3 = h0 + t3 / 14;
#pragma unroll
          for (int r = 0; r < 4; ++r) {
            size_t pix = (size_t)(b * 224 + hglob3) * 224 + cb3 + q * 4 + r;
            xres[r] = xs32[pix * 16 + c16];
          }
        }
        if (j >= 1 && j <= 14) {        // G2 half-N on tiles 2(j-1), 2(j-1)+1
          const short* srcA = sBUF + (((j - 1) & 1) * 2 + 0) * 2176;
          const short* srcB = sBUF + (((j - 1) & 1) * 2 + 1) * 2176;
          float4v acc2[2][4];
#pragma unroll
          for (int tt = 0; tt < 2; ++tt)
#pragma unroll
            for (int n = 0; n < 4; ++n) acc2[tt][n] = (float4v){0.f, 0.f, 0.f, 0.f};
#pragma unroll
          for (int kc = 0; kc < 4; ++kc) {
            short8 aA = *(const short8*)(srcA + c16 * 136 + kc * 32 + q8);
            short8 aB = *(const short8*)(srcB + c16 * 136 + kc * 32 + q8);
#pragma unroll
            for (int n = 0; n < 4; ++n) {
              acc2[0][n] = MFMA16(aA, w2f[kc][n], acc2[0][n]);
              acc2[1][n] = MFMA16(aB, w2f[kc][n], acc2[1][n]);
            }
          }
#pragma unroll
          for (int tt = 0; tt < 2; ++tt) {
            short* dsth2 = sH2 + ((j & 1) * 2 + tt) * 2176;
#pragma unroll
            for (int r = 0; r < 4; ++r) {
              uint2v pk;
              pk[0] = pk2bf(fmaxf(acc2[tt][0][r] + bG[0], 0.f),
                            fmaxf(acc2[tt][1][r] + bG[1], 0.f));
              pk[1] = pk2bf(fmaxf(acc2[tt][2][r] + bG[2], 0.f),
                            fmaxf(acc2[tt][3][r] + bG[3], 0.f));
              *(uint2v*)(dsth2 + (q * 4 + r) * 136 + c16 * 8 + g * 4) = pk;
            }
          }
        }
        if (j >= 2) {                   // G3 full-K + epilogue, tile 2(j-2)+g
          const short* srch2 = sH2 + (((j - 1) & 1) * 2 + g) * 2176;
          float4v acc3 = (float4v){0.f, 0.f, 0.f, 0.f};
#pragma unroll
          for (int kc = 0; kc < 4; ++kc) {
            short8 a = *(const short8*)(srch2 + c16 * 136 + kc * 32 + q8);
            acc3 = MFMA16(a, w3f[kc], acc3);
          }
#pragma unroll
          for (int r = 0; r < 4; ++r) {
            int col = cb3 + q * 4 + r;
            size_t pix = (size_t)(b * 224 + hglob3) * 224 + col;
            float v = xres[r] + acc3[r];
            v = fminf(fmaxf(v, 0.f), 1.f);
            if (last) {
              dout[((size_t)(b * 16 + c16) * 224 + hglob3) * 224 + col] = v;
            } else {
              xd32[pix * 16 + c16] = v;
              xd16[pix * 16 + c16] = f2bf(v);
            }
          }
        }
        sync_lds();                     // [1..16]
      }
      barrier_full();                   // [C] epilogue stores drained
      // publish is done by tid0 (G1 branch)
    }
  }
}

// ---------------------------------------------------------------------------
extern "C" void kernel_launch(void* const* d_in, const int* in_sizes, int n_in,
                              void* d_out, int out_size, void* d_ws, size_t ws_size,
                              hipStream_t stream) {
  const float* x  = (const float*)d_in[0];
  const float* wp = (const float*)d_in[1];
  const float* w1 = (const float*)d_in[2];
  const float* b1 = (const float*)d_in[3];
  const float* w2 = (const float*)d_in[4];
  const float* b2 = (const float*)d_in[5];
  const float* w3 = (const float*)d_in[6];

  char* ws = (char*)d_ws;
  short* wEg = (short*)(ws + WS_WE);
  short* w2g = (short*)(ws + WS_W2);
  short* w3g = (short*)(ws + WS_W3);
  float* b1p = (float*)(ws + WS_B1);
  float* b2p = (float*)(ws + WS_B2);
  float* X32a = (float*)(ws + WS_X32A);
  float* X32b = (float*)(ws + WS_X32B);
  short* X16a = (short*)(ws + WS_X16A);
  short* X16b = (short*)(ws + WS_X16B);
  unsigned* done = (unsigned*)(ws + WS_DONE);

  prep_x<<<12544, 256, 0, stream>>>(x, X32a, X16a, done);
  prep_w<<<163, 256, 0, stream>>>(wp, w1, b1, w2, b2, w3, wEg, w2g, w3g, b1p, b2p);

  ca_persist<<<448, 256, 0, stream>>>(wEg, w2g, w3g, b1p, b2p,
                                      X32a, X16a, X32b, X16b,
                                      (float*)d_out, done);
}

// Round 8
// 1007.298 us; speedup vs baseline: 4.9570x; 1.4046x over previous
//
#include <hip/hip_runtime.h>

// ---------------------------------------------------------------------------
// NeuralCA fused step, multi-launch, 4 waves/SIMD:
//   512-thread blocks (8 waves), 2-row blocks, 448 blocks, 2 blocks/CU
//   (63.7 KB LDS), __launch_bounds__(512,4) -> VGPR cap 128/wave.
//   waves 0-3 (G1, quarter wq): h1 chans 32wq..32wq+31 of tiles {2j,2j+1},
//        W_eff quarter = 10 frags (40 VGPR)
//   waves 4-7 (G23, quarter g): G2 chans 32g..+31 of tiles {2(j-1),2(j-1)+1};
//        waves g<2 also: G3 full-K + epilogue of tile 2(j-2)+g
//   h1/h2 via double-buffered LDS mailboxes, 1 lgkm-only barrier per iter.
//   Per-wave VGPR ~95-110 << 128 cap => weights stay register-resident
//   (R5-R7 lesson: arrays living across a persistent outer loop get demoted;
//   per-launch loads at VGPR 220 stayed resident in R2-R4).
// ---------------------------------------------------------------------------

typedef __attribute__((ext_vector_type(8))) short short8;
typedef __attribute__((ext_vector_type(4))) float float4v;
typedef __attribute__((ext_vector_type(2))) float float2v;

#define MFMA16(a, b, c) __builtin_amdgcn_mfma_f32_16x16x32_bf16((a), (b), (c), 0, 0, 0)

__device__ __forceinline__ short f2bf(float f) {
  unsigned u = __builtin_bit_cast(unsigned, f);
  return (short)((u + 0x8000u) >> 16);     // round-half-up
}

__device__ __forceinline__ unsigned pk2bf(float a, float b) {
#if __has_builtin(__builtin_amdgcn_cvt_pk_bf16_f32)
  typedef __attribute__((ext_vector_type(2))) __bf16 bf2;
  bf2 r = __builtin_amdgcn_cvt_pk_bf16_f32(a, b);
  return __builtin_bit_cast(unsigned, r);
#else
  unsigned ua = __builtin_bit_cast(unsigned, a), ub = __builtin_bit_cast(unsigned, b);
  return ((ua + 0x8000u) >> 16) | (((ub + 0x8000u) >> 16) << 16);
#endif
}

__device__ __forceinline__ void async16(const void* g, void* l) {
  __builtin_amdgcn_global_load_lds((const __attribute__((address_space(1))) void*)g,
                                   (__attribute__((address_space(3))) void*)l,
                                   16, 0, 0);
}

// LDS-only barrier (no vmcnt drain - global stores fly free)
__device__ __forceinline__ void sync_lds() {
  asm volatile("s_waitcnt lgkmcnt(0)\n\ts_barrier" ::: "memory");
}

// ---- workspace layout (bytes) ----
#define WS_WE    0          // W_eff^T [128][168] bf16 (K pad 144->168, zeros)
#define WS_W2    43008      // W2^T    [128][136] bf16 (K sigma-permuted)
#define WS_W3    77824      // W3^T    [ 16][136] bf16 (sigma-perm, pad 2560)
#define WS_B1    82944      // b1 sigma-permuted f32 [128]
#define WS_B2    83456      // b2 sigma-permuted f32 [128]
#define WS_X32A  83968
#define WS_X32B  12929024
#define WS_X16A  25774080
#define WS_X16B  32196608

// ---------------------------------------------------------------------------
__global__ void prep_x(const float* __restrict__ x, float* __restrict__ x32,
                       short* __restrict__ x16) {
  int i = blockIdx.x * 256 + threadIdx.x;          // exactly 3211264 threads
  int w = i % 224;
  int h = (i / 224) % 224;
  int c = (i / 50176) & 15;
  int bb = i / 802816;
  float v = x[i];
  int o = ((bb * 224 + h) * 224 + w) * 16 + c;     // NHWC
  x32[o] = v;
  x16[o] = f2bf(v);
}

// sigma: stored position p holds channel chan(p) = 16*(p&7) + (p>>3)
__global__ void prep_w(const float* __restrict__ wp, const float* __restrict__ w1,
                       const float* __restrict__ b1, const float* __restrict__ w2,
                       const float* __restrict__ b2, const float* __restrict__ w3,
                       short* __restrict__ wE, short* __restrict__ w2t,
                       short* __restrict__ w3t, float* __restrict__ b1p,
                       float* __restrict__ b2p) {
  int i = blockIdx.x * 256 + threadIdx.x;          // exactly 41728 threads
  if (i < 21504) {                                  // W_eff^T [o=128][k=168]
    int o = i / 168, k = i % 168;
    float v = 0.f;
    if (k < 144) {
      int off = k >> 4, c = k & 15;                 // k = offset*16 + c
      for (int c3 = 0; c3 < 48; ++c3)
        v += w1[o * 48 + c3] * wp[c3 * 144 + c * 9 + off];
    }
    wE[i] = f2bf(v);
  } else if (i < 38912) {                           // W2^T perm [n=128][kk=136]
    int j = i - 21504;
    int n = j / 136, kk = j % 136;
    float v = 0.f;
    if (kk < 128) { int ch = 16 * (kk & 7) + (kk >> 3); v = w2[n * 128 + ch]; }
    w2t[j] = f2bf(v);
  } else if (i < 41472) {                           // W3^T perm, padded to 2560
    int j = i - 38912;
    float v = 0.f;
    if (j < 2176) {
      int n = j / 136, kk = j % 136;
      if (kk < 128) { int ch = 16 * (kk & 7) + (kk >> 3); v = w3[n * 128 + ch]; }
    }
    w3t[j] = f2bf(v);
  } else if (i < 41600) {
    int p = i - 41472;
    b1p[p] = b1[16 * (p & 7) + (p >> 3)];
  } else {
    int p = i - 41600;
    b2p[p] = b2[16 * (p & 7) + (p >> 3)];
  }
}

// ---------------------------------------------------------------------------
// One CA step. Block = 2 image rows, 512 threads = 8 waves. 28 tiles of
// 16 px; pipeline over 16 iterations:
//   G1 wave wq:  iter j<14:     chan-quarter of h1, tiles {2j,2j+1} -> sBUF j&1
//   G23 wave g:  iter 1<=j<=14: chan-quarter of h2, tiles {2(j-1),..} -> sH2 j&1
//   G23 g<2:     iter j>=2:     G3 full-K + epilogue, tile 2(j-2)+g
template <bool LAST>
__global__ __launch_bounds__(512, 4) void ca_step(
    const short* __restrict__ wEg, const short* __restrict__ w2g,
    const short* __restrict__ w3g, const float* __restrict__ b1p,
    const float* __restrict__ b2p, const float* __restrict__ xs32,
    const short* __restrict__ xs16, float* __restrict__ xd32,
    short* __restrict__ xd16, float* __restrict__ dout) {
  __shared__ short sXH[4 * 3616];       // 28928 B  halo: 4 rows x 226 x 16ch
  __shared__ short sBUF[2 * 2 * 2176];  // 17408 B  h1 mailbox dbuf x 2 tiles
  __shared__ short sH2[2 * 2 * 2176];   // 17408 B  h2 dbuf x 2 tiles
  // total 63744 B -> 2 blocks/CU, 16 waves/CU = 4 waves/SIMD

  const int tid = threadIdx.x;
  const int lane = tid & 63;
  const int wv = tid >> 6;              // 0..7
  const int c16 = lane & 15;
  const int q = lane >> 4;
  const int q8 = q * 8;
  const int qh = q >> 1;
  const int c0 = (q & 1) * 8;

  const int blk = blockIdx.x;           // 448 = 4 batches x 112 rowgroups
  const int b = blk / 112;
  const int h0 = (blk % 112) * 2;

  // ---- stage halo: 4 rows x 7 chunks (1KB each); OOB rows -> zeros ----
  const short8 z8 = {0, 0, 0, 0, 0, 0, 0, 0};
  for (int t = wv; t < 28; t += 8) {
    int hr = t / 7, ck = t % 7;
    int hh = h0 - 1 + hr;
    char* l = (char*)sXH + hr * 7232 + 32 + ck * 1024;  // col 0 = image col -1
    if (hh >= 0 && hh < 224) {
      const char* g = (const char*)xs16 + ((size_t)(b * 224 + hh) * 224) * 32 + ck * 1024;
      async16(g + lane * 16, l);
    } else {
      *(short8*)(l + lane * 16) = z8;
    }
  }
  if (tid < 16) {   // zero edge columns (image col -1 and 224) for all 4 rows
    int hr = tid >> 2, wch = tid & 3;
    int colb = (wch < 2) ? 0 : 225;
    *(short8*)((char*)sXH + hr * 7232 + colb * 32 + (wch & 1) * 16) = z8;
  }

  if (wv < 4) {
    // ====== G1 role, chan-quarter wq: conv3x3+MLP1 fused =================
    const int wq = wv;
    short8 wf[5][2];                    // 40 VGPR
#pragma unroll
    for (int kc = 0; kc < 5; ++kc)
#pragma unroll
      for (int n = 0; n < 2; ++n)
        wf[kc][n] = *(const short8*)(wEg + ((2 * wq + n) * 16 + c16) * 168 + kc * 32 + q8);
    const float2v bH = *(const float2v*)(b1p + c16 * 8 + 2 * wq);

    __syncthreads();                    // halo ready (drains vmcnt)

    for (int j = 0; j < 16; ++j) {
      if (j < 14) {
        const int t0 = 2 * j, t1 = t0 + 1;
        const int hb0 = ((t0 / 14) * 226 + (t0 % 14) * 16) * 16;
        const int hb1 = ((t1 / 14) * 226 + (t1 % 14) * 16) * 16;
        float4v acc[2][2];
#pragma unroll
        for (int tt = 0; tt < 2; ++tt)
#pragma unroll
          for (int n = 0; n < 2; ++n) acc[tt][n] = (float4v){0.f, 0.f, 0.f, 0.f};
#pragma unroll
        for (int kc = 0; kc < 5; ++kc) {
          int off = kc * 2 + qh;
          if (off > 8) off = 8;         // K 144..159 hit zero rows of W_eff
          int dy = (off * 11) >> 5;     // off/3
          int dxx = off - dy * 3;
          const int ao = (dy * 226 + dxx + c16) * 16 + c0;
          short8 a0 = *(const short8*)(sXH + hb0 + ao);
          short8 a1 = *(const short8*)(sXH + hb1 + ao);
#pragma unroll
          for (int n = 0; n < 2; ++n) {
            acc[0][n] = MFMA16(a0, wf[kc][n], acc[0][n]);
            acc[1][n] = MFMA16(a1, wf[kc][n], acc[1][n]);
          }
        }
#pragma unroll
        for (int tt = 0; tt < 2; ++tt) {
          short* dst = sBUF + ((j & 1) * 2 + tt) * 2176;
#pragma unroll
          for (int r = 0; r < 4; ++r) {
            unsigned d = pk2bf(fmaxf(acc[tt][0][r] + bH[0], 0.f),
                               fmaxf(acc[tt][1][r] + bH[1], 0.f));
            *(unsigned*)(dst + (q * 4 + r) * 136 + c16 * 8 + 2 * wq) = d;
          }
        }
      }
      sync_lds();
    }
  } else {
    // ====== G23 role, chan-quarter g: MLP2 quarter + (g<2) MLP3/update ===
    const int g = wv - 4;
    short8 w2f[4][2];                   // 32 VGPR
    short8 w3f[4];                      // 16 VGPR
#pragma unroll
    for (int kc = 0; kc < 4; ++kc)
#pragma unroll
      for (int n = 0; n < 2; ++n)
        w2f[kc][n] = *(const short8*)(w2g + ((2 * g + n) * 16 + c16) * 136 + kc * 32 + q8);
#pragma unroll
    for (int kc = 0; kc < 4; ++kc)
      w3f[kc] = *(const short8*)(w3g + c16 * 136 + kc * 32 + q8);
    const float2v bG = *(const float2v*)(b2p + c16 * 8 + 2 * g);

    __syncthreads();                    // halo ready

    for (int j = 0; j < 16; ++j) {
      float xres[4];
      int cb3 = 0, hglob3 = 0;
      if (g < 2 && j >= 2) {            // prefetch residual x for G3's tile
        const int t3 = 2 * (j - 2) + g;
        cb3 = (t3 % 14) * 16; hglob3 = h0 + t3 / 14;
#pragma unroll
        for (int r = 0; r < 4; ++r) {
          size_t pix = (size_t)(b * 224 + hglob3) * 224 + cb3 + q * 4 + r;
          xres[r] = xs32[pix * 16 + c16];
        }
      }
      if (j >= 1 && j <= 14) {          // G2 quarter on tiles 2(j-1), 2(j-1)+1
        const short* srcA = sBUF + (((j - 1) & 1) * 2 + 0) * 2176;
        const short* srcB = sBUF + (((j - 1) & 1) * 2 + 1) * 2176;
        float4v acc2[2][2];
#pragma unroll
        for (int tt = 0; tt < 2; ++tt)
#pragma unroll
          for (int n = 0; n < 2; ++n) acc2[tt][n] = (float4v){0.f, 0.f, 0.f, 0.f};
#pragma unroll
        for (int kc = 0; kc < 4; ++kc) {
          short8 aA = *(const short8*)(srcA + c16 * 136 + kc * 32 + q8);
          short8 aB = *(const short8*)(srcB + c16 * 136 + kc * 32 + q8);
#pragma unroll
          for (int n = 0; n < 2; ++n) {
            acc2[0][n] = MFMA16(aA, w2f[kc][n], acc2[0][n]);
            acc2[1][n] = MFMA16(aB, w2f[kc][n], acc2[1][n]);
          }
        }
#pragma unroll
        for (int tt = 0; tt < 2; ++tt) {
          short* dsth2 = sH2 + ((j & 1) * 2 + tt) * 2176;
#pragma unroll
          for (int r = 0; r < 4; ++r) {
            unsigned d = pk2bf(fmaxf(acc2[tt][0][r] + bG[0], 0.f),
                               fmaxf(acc2[tt][1][r] + bG[1], 0.f));
            *(unsigned*)(dsth2 + (q * 4 + r) * 136 + c16 * 8 + 2 * g) = d;
          }
        }
      }
      if (g < 2 && j >= 2) {            // G3 full-K + epilogue, tile 2(j-2)+g
        const short* srch2 = sH2 + (((j - 1) & 1) * 2 + g) * 2176;
        float4v acc3 = (float4v){0.f, 0.f, 0.f, 0.f};
#pragma unroll
        for (int kc = 0; kc < 4; ++kc) {
          short8 a = *(const short8*)(srch2 + c16 * 136 + kc * 32 + q8);
          acc3 = MFMA16(a, w3f[kc], acc3);
        }
#pragma unroll
        for (int r = 0; r < 4; ++r) {
          int col = cb3 + q * 4 + r;
          size_t pix = (size_t)(b * 224 + hglob3) * 224 + col;
          float v = xres[r] + acc3[r];
          v = fminf(fmaxf(v, 0.f), 1.f);
          if (LAST) {
            dout[((size_t)(b * 16 + c16) * 224 + hglob3) * 224 + col] = v;  // NCHW
          } else {
            xd32[pix * 16 + c16] = v;
            xd16[pix * 16 + c16] = f2bf(v);
          }
        }
      }
      sync_lds();
    }
  }
}

// ---------------------------------------------------------------------------
extern "C" void kernel_launch(void* const* d_in, const int* in_sizes, int n_in,
                              void* d_out, int out_size, void* d_ws, size_t ws_size,
                              hipStream_t stream) {
  const float* x  = (const float*)d_in[0];
  const float* wp = (const float*)d_in[1];
  const float* w1 = (const float*)d_in[2];
  const float* b1 = (const float*)d_in[3];
  const float* w2 = (const float*)d_in[4];
  const float* b2 = (const float*)d_in[5];
  const float* w3 = (const float*)d_in[6];

  char* ws = (char*)d_ws;
  short* wEg = (short*)(ws + WS_WE);
  short* w2g = (short*)(ws + WS_W2);
  short* w3g = (short*)(ws + WS_W3);
  float* b1p = (float*)(ws + WS_B1);
  float* b2p = (float*)(ws + WS_B2);
  float* X32[2] = {(float*)(ws + WS_X32A), (float*)(ws + WS_X32B)};
  short* X16[2] = {(short*)(ws + WS_X16A), (short*)(ws + WS_X16B)};

  prep_x<<<12544, 256, 0, stream>>>(x, X32[0], X16[0]);
  prep_w<<<163, 256, 0, stream>>>(wp, w1, b1, w2, b2, w3, wEg, w2g, w3g, b1p, b2p);

  for (int s = 0; s < 39; ++s) {
    int sb = s & 1;
    ca_step<false><<<448, 512, 0, stream>>>(wEg, w2g, w3g, b1p, b2p,
                                            X32[sb], X16[sb],
                                            X32[1 - sb], X16[1 - sb], nullptr);
  }
  ca_step<true><<<448, 512, 0, stream>>>(wEg, w2g, w3g, b1p, b2p,
                                         X32[1], X16[1],
                                         X32[0], X16[0], (float*)d_out);
}